// Round 12
// baseline (150.247 us; speedup 1.0000x reference)
//
#include <hip/hip_runtime.h>

// MOLGCirculantLinear R11: R10 structure + occupancy push.
// x[512][1024] f32, w[128][128][8] f32, scale[64][8] f32.
// d_out = out[512][1024] ++ phase[512][128][128][8].
//
// Block = 4 waves = 4 different b, same 4-gy strip; w rows (16KB) in LDS.
// R11 changes vs R10: __launch_bounds__(256,8) targeting <=64 VGPR so 8
// waves/SIMD are resident (R10 ~4-5): decorrelates CU-level compute/store
// convoys so HBM drain overlaps VALU. Clamp via v_med3 (fmed3f).

#define NB   512
#define NGY  128
#define NGX  128
#define NK   8

typedef float f32x4 __attribute__((ext_vector_type(4)));

__global__ __launch_bounds__(256, 8) void molg_lds(
    const float* __restrict__ x,
    const float* __restrict__ w,
    const float* __restrict__ scale,
    float* __restrict__ d_out)
{
    __shared__ f32x4 lw[1024];               // 4 gy rows x 1024 floats = 16KB

    const int tid  = threadIdx.x;
    const int lane = tid & 63;
    const int wv   = tid >> 6;               // 0..3 -> which b
    const int bg   = blockIdx.x >> 5;        // 0..127 b-group
    const int gs   = blockIdx.x & 31;        // 0..31 gy-strip
    const int b    = bg * 4 + wv;
    const int gy0  = gs * 4;

    const int gxs = lane >> 1;               // 0..31
    const int kq  = lane & 1;                // k-half

    float* out   = d_out;
    float* phase = d_out + (size_t)NB * NGY * NK;

    const float c0 = 0.02403f, c1 = -0.2699f, c2 = 1.17f,
                c3 = -2.454f,  c4 = 2.523f,  c5 = -0.08003f;

    // ---- stage w rows gy0..gy0+3 into LDS (4096 floats, coalesced) ----
    {
        const f32x4* wsrc = reinterpret_cast<const f32x4*>(w + (size_t)gy0 * NGX * NK);
#pragma unroll
        for (int u = 0; u < 4; ++u)
            lw[tid + 256 * u] = wsrc[tid + 256 * u];
    }

    // ---- per-wave preload: x^2 rotated by 4*kq, for 4 gx positions ----
    float y[4][NK];
#pragma unroll
    for (int it = 0; it < 4; ++it) {
        const int gx = 32 * it + gxs;
        const f32x4* xp = reinterpret_cast<const f32x4*>(x + (size_t)b * 1024 + gx * NK);
        f32x4 a = xp[0], c = xp[1];
        float t[NK] = {a[0]*a[0], a[1]*a[1], a[2]*a[2], a[3]*a[3],
                       c[0]*c[0], c[1]*c[1], c[2]*c[2], c[3]*c[3]};
#pragma unroll
        for (int q = 0; q < NK; ++q)
            y[it][q] = kq ? t[(q + 4) & 7] : t[q];
    }

    // scale: gx&63 = gxs (it even) or gxs+32 (it odd)
    const f32x4 sve = *reinterpret_cast<const f32x4*>(scale + (size_t)gxs * NK + 4 * kq);
    const f32x4 svo = *reinterpret_cast<const f32x4*>(scale + (size_t)(gxs + 32) * NK + 4 * kq);

    float acc[4][4];
#pragma unroll
    for (int j = 0; j < 4; ++j)
#pragma unroll
        for (int q = 0; q < 4; ++q) acc[j][q] = 0.f;

    __syncthreads();

    // phase rows gy0..gy0+3 for this wave's b: base + j*256 + it*64 (f32x4)
    f32x4* pbase4 = reinterpret_cast<f32x4*>(
        phase + (((size_t)b * NGY + gy0) * NGX) * NK);

#pragma unroll
    for (int s = 0; s < 16; ++s) {
        const int j = s >> 2, it = s & 3;

        // w from LDS: both lanes of a pair read the same 32B (2-way bcast, free)
        const f32x4 wa = lw[j * 256 + it * 64 + gxs * 2];
        const f32x4 wc = lw[j * 256 + it * 64 + gxs * 2 + 1];
        const float wf[NK] = {wa[0], wa[1], wa[2], wa[3], wc[0], wc[1], wc[2], wc[3]};

        float xr[4];
#pragma unroll
        for (int n = 0; n < 4; ++n) {
            float s_ = 0.f;
#pragma unroll
            for (int m = 0; m < NK; ++m)
                s_ = fmaf(wf[m], y[it][(n - m) & 7], s_);
            xr[n] = s_;
        }

        // dense 1KB line-aligned burst: lane i -> byte 16*i (nontemporal)
        f32x4 q = {xr[0], xr[1], xr[2], xr[3]};
        __builtin_nontemporal_store(q, pbase4 + j * 256 + it * 64 + lane);

        const f32x4 sv = (it & 1) ? svo : sve;
#pragma unroll
        for (int n = 0; n < 4; ++n) {
            float v = xr[n];
            float p = fmaf(c0, v, c1);
            p = fmaf(p, v, c2);
            p = fmaf(p, v, c3);
            p = fmaf(p, v, c4);
            p = fmaf(p, v, c5);
            p = __builtin_amdgcn_fmed3f(p, 0.f, 1.f);   // clamp [0,1]
            acc[j][n] = fmaf(p, sv[n], acc[j][n]);
        }
    }

    // ---- tail: stage-major butterflies (16 independent shuffles per stage) ----
#pragma unroll
    for (int off = 2; off < 64; off <<= 1)
#pragma unroll
        for (int j = 0; j < 4; ++j)
#pragma unroll
            for (int n = 0; n < 4; ++n)
                acc[j][n] += __shfl_xor(acc[j][n], off, 64);

#pragma unroll
    for (int j = 0; j < 4; ++j) {
        if (lane < 2) {   // lane0: k0..3, lane1: k4..7
            f32x4 v = {fmaf(2.f, acc[j][0], -128.f), fmaf(2.f, acc[j][1], -128.f),
                       fmaf(2.f, acc[j][2], -128.f), fmaf(2.f, acc[j][3], -128.f)};
            *(reinterpret_cast<f32x4*>(out + (size_t)b * 1024 + (gy0 + j) * NK) + lane) = v;
        }
    }
}

extern "C" void kernel_launch(void* const* d_in, const int* in_sizes, int n_in,
                              void* d_out, int out_size, void* d_ws, size_t ws_size,
                              hipStream_t stream) {
    const float* x     = (const float*)d_in[0];
    const float* w     = (const float*)d_in[1];
    const float* scale = (const float*)d_in[2];
    float* out = (float*)d_out;

    dim3 grid(4096);    // 128 b-groups x 32 gy-strips; 4 waves = 4 b per block
    dim3 block(256);
    hipLaunchKernelGGL(molg_lds, grid, block, 0, stream, x, w, scale, out);
}

// Round 13
// 90.592 us; speedup vs baseline: 1.6585x; 1.6585x over previous
//
#include <hip/hip_runtime.h>

// MOLGCirculantLinear R12: R10 structure, register-slimmed for residency.
// x[512][1024] f32, w[128][128][8] f32, scale[64][8] f32.
// d_out = out[512][1024] ++ phase[512][128][128][8].
//
// Block = 4 waves = 4 different b, same 4-gy strip; w rows (16KB) in LDS.
// R12 vs R10: main loop split into 2 halves; y holds only 2 gx-iterations
// (16 VGPR not 32), x reloaded between halves (L2-hit); sched_barrier keeps
// the halves separate so peak VGPR ~75. __launch_bounds__(256,6) (cap 85)
// -> ~6 waves/SIMD resident without spill (R11's (256,8) forced 32 VGPR +
// 173MB scratch reads = disaster). Accumulation order bit-identical to R10.

#define NB   512
#define NGY  128
#define NGX  128
#define NK   8

typedef float f32x4 __attribute__((ext_vector_type(4)));

__global__ __launch_bounds__(256, 6) void molg_lds(
    const float* __restrict__ x,
    const float* __restrict__ w,
    const float* __restrict__ scale,
    float* __restrict__ d_out)
{
    __shared__ f32x4 lw[1024];               // 4 gy rows x 1024 floats = 16KB

    const int tid  = threadIdx.x;
    const int lane = tid & 63;
    const int wv   = tid >> 6;               // 0..3 -> which b
    const int bg   = blockIdx.x >> 5;        // 0..127 b-group
    const int gs   = blockIdx.x & 31;        // 0..31 gy-strip
    const int b    = bg * 4 + wv;
    const int gy0  = gs * 4;

    const int gxs = lane >> 1;               // 0..31
    const int kq  = lane & 1;                // k-half

    float* out   = d_out;
    float* phase = d_out + (size_t)NB * NGY * NK;

    const float c0 = 0.02403f, c1 = -0.2699f, c2 = 1.17f,
                c3 = -2.454f,  c4 = 2.523f,  c5 = -0.08003f;

    // ---- stage w rows gy0..gy0+3 into LDS (4096 floats, coalesced) ----
    {
        const f32x4* wsrc = reinterpret_cast<const f32x4*>(w + (size_t)gy0 * NGX * NK);
#pragma unroll
        for (int u = 0; u < 4; ++u)
            lw[tid + 256 * u] = wsrc[tid + 256 * u];
    }

    // scale: gx&63 = gxs (it even) or gxs+32 (it odd)
    const f32x4 sve = *reinterpret_cast<const f32x4*>(scale + (size_t)gxs * NK + 4 * kq);
    const f32x4 svo = *reinterpret_cast<const f32x4*>(scale + (size_t)(gxs + 32) * NK + 4 * kq);

    float acc[4][4];
#pragma unroll
    for (int j = 0; j < 4; ++j)
#pragma unroll
        for (int q = 0; q < 4; ++q) acc[j][q] = 0.f;

    __syncthreads();

    // phase rows gy0..gy0+3 for this wave's b: base + j*256 + it*64 (f32x4)
    f32x4* pbase4 = reinterpret_cast<f32x4*>(
        phase + (((size_t)b * NGY + gy0) * NGX) * NK);

#pragma unroll
    for (int half = 0; half < 2; ++half) {
        __builtin_amdgcn_sched_barrier(0);   // keep halves separate (VGPR cap)

        // x^2 rotated by 4*kq for this half's 2 gx positions
        float y[2][NK];
#pragma unroll
        for (int itl = 0; itl < 2; ++itl) {
            const int gx = 32 * (2 * half + itl) + gxs;
            const f32x4* xp = reinterpret_cast<const f32x4*>(x + (size_t)b * 1024 + gx * NK);
            f32x4 a = xp[0], c = xp[1];
            float t[NK] = {a[0]*a[0], a[1]*a[1], a[2]*a[2], a[3]*a[3],
                           c[0]*c[0], c[1]*c[1], c[2]*c[2], c[3]*c[3]};
#pragma unroll
            for (int q = 0; q < NK; ++q)
                y[itl][q] = kq ? t[(q + 4) & 7] : t[q];
        }

#pragma unroll
        for (int j = 0; j < 4; ++j) {
#pragma unroll
            for (int itl = 0; itl < 2; ++itl) {
                const int it = 2 * half + itl;

                // w from LDS: lane pairs read the same 32B (2-way bcast, free)
                const f32x4 wa = lw[j * 256 + it * 64 + gxs * 2];
                const f32x4 wc = lw[j * 256 + it * 64 + gxs * 2 + 1];
                const float wf[NK] = {wa[0], wa[1], wa[2], wa[3],
                                      wc[0], wc[1], wc[2], wc[3]};

                float xr[4];
#pragma unroll
                for (int n = 0; n < 4; ++n) {
                    float s_ = 0.f;
#pragma unroll
                    for (int m = 0; m < NK; ++m)
                        s_ = fmaf(wf[m], y[itl][(n - m) & 7], s_);
                    xr[n] = s_;
                }

                // dense 1KB line-aligned burst: lane i -> byte 16*i
                f32x4 q = {xr[0], xr[1], xr[2], xr[3]};
                __builtin_nontemporal_store(q, pbase4 + j * 256 + it * 64 + lane);

                const f32x4 sv = (it & 1) ? svo : sve;
#pragma unroll
                for (int n = 0; n < 4; ++n) {
                    float v = xr[n];
                    float p = fmaf(c0, v, c1);
                    p = fmaf(p, v, c2);
                    p = fmaf(p, v, c3);
                    p = fmaf(p, v, c4);
                    p = fmaf(p, v, c5);
                    p = __builtin_amdgcn_fmed3f(p, 0.f, 1.f);   // clamp [0,1]
                    acc[j][n] = fmaf(p, sv[n], acc[j][n]);
                }
            }
        }
    }

    // ---- tail: stage-major butterflies (16 independent shuffles per stage) ----
#pragma unroll
    for (int off = 2; off < 64; off <<= 1)
#pragma unroll
        for (int j = 0; j < 4; ++j)
#pragma unroll
            for (int n = 0; n < 4; ++n)
                acc[j][n] += __shfl_xor(acc[j][n], off, 64);

#pragma unroll
    for (int j = 0; j < 4; ++j) {
        if (lane < 2) {   // lane0: k0..3, lane1: k4..7
            f32x4 v = {fmaf(2.f, acc[j][0], -128.f), fmaf(2.f, acc[j][1], -128.f),
                       fmaf(2.f, acc[j][2], -128.f), fmaf(2.f, acc[j][3], -128.f)};
            *(reinterpret_cast<f32x4*>(out + (size_t)b * 1024 + (gy0 + j) * NK) + lane) = v;
        }
    }
}

extern "C" void kernel_launch(void* const* d_in, const int* in_sizes, int n_in,
                              void* d_out, int out_size, void* d_ws, size_t ws_size,
                              hipStream_t stream) {
    const float* x     = (const float*)d_in[0];
    const float* w     = (const float*)d_in[1];
    const float* scale = (const float*)d_in[2];
    float* out = (float*)d_out;

    dim3 grid(4096);    // 128 b-groups x 32 gy-strips; 4 waves = 4 b per block
    dim3 block(256);
    hipLaunchKernelGGL(molg_lds, grid, block, 0, stream, x, w, scale, out);
}

// Round 14
// 53.265 us; speedup vs baseline: 2.8207x; 1.7008x over previous
//
#include <hip/hip_runtime.h>

// MOLGCirculantLinear R13: R10 structure + packed-fp32 (v_pk_fma_f32) math.
// x[512][1024] f32, w[128][128][8] f32, scale[64][8] f32.
// d_out = out[512][1024] ++ phase[512][128][128][8].
//
// Block = 4 waves = 4 different b, same 4-gy strip; w rows (16KB) in LDS;
// dense 1KB nt store bursts; stage-major butterfly tail (all == R10, 52.7us).
// R13 change: conv + poly + scale-acc computed on f32x2 pairs via
// __builtin_elementwise_fma -> v_pk_fma_f32, halving VALU instruction count
// (~60 -> ~38 per step). Per-element FMA order identical to R10 -> absmax 1.0.

#define NB   512
#define NGY  128
#define NGX  128
#define NK   8

typedef float f32x4 __attribute__((ext_vector_type(4)));
typedef float f32x2 __attribute__((ext_vector_type(2)));

__global__ __launch_bounds__(256, 4) void molg_pk(
    const float* __restrict__ x,
    const float* __restrict__ w,
    const float* __restrict__ scale,
    float* __restrict__ d_out)
{
    __shared__ f32x4 lw[1024];               // 4 gy rows x 1024 floats = 16KB

    const int tid  = threadIdx.x;
    const int lane = tid & 63;
    const int wv   = tid >> 6;               // 0..3 -> which b
    const int bg   = blockIdx.x >> 5;        // 0..127 b-group
    const int gs   = blockIdx.x & 31;        // 0..31 gy-strip
    const int b    = bg * 4 + wv;
    const int gy0  = gs * 4;

    const int gxs = lane >> 1;               // 0..31
    const int kq  = lane & 1;                // k-half

    float* out   = d_out;
    float* phase = d_out + (size_t)NB * NGY * NK;

    // ---- stage w rows gy0..gy0+3 into LDS (4096 floats, coalesced) ----
    {
        const f32x4* wsrc = reinterpret_cast<const f32x4*>(w + (size_t)gy0 * NGX * NK);
#pragma unroll
        for (int u = 0; u < 4; ++u)
            lw[tid + 256 * u] = wsrc[tid + 256 * u];
    }

    // ---- per-wave preload: x^2 rotated by 4*kq, for 4 gx positions ----
    float y[4][NK];
#pragma unroll
    for (int it = 0; it < 4; ++it) {
        const int gx = 32 * it + gxs;
        const f32x4* xp = reinterpret_cast<const f32x4*>(x + (size_t)b * 1024 + gx * NK);
        f32x4 a = xp[0], c = xp[1];
        f32x4 a2 = a * a, c2 = c * c;        // v_pk_mul_f32
        float t[NK] = {a2[0], a2[1], a2[2], a2[3], c2[0], c2[1], c2[2], c2[3]};
#pragma unroll
        for (int q = 0; q < NK; ++q)
            y[it][q] = kq ? t[(q + 4) & 7] : t[q];
    }

    // scale: gx&63 = gxs (it even) or gxs+32 (it odd)
    const f32x4 sve = *reinterpret_cast<const f32x4*>(scale + (size_t)gxs * NK + 4 * kq);
    const f32x4 svo = *reinterpret_cast<const f32x4*>(scale + (size_t)(gxs + 32) * NK + 4 * kq);
    const f32x2 sve01 = {sve[0], sve[1]}, sve23 = {sve[2], sve[3]};
    const f32x2 svo01 = {svo[0], svo[1]}, svo23 = {svo[2], svo[3]};

    f32x2 acc01[4], acc23[4];
#pragma unroll
    for (int j = 0; j < 4; ++j) {
        acc01[j] = (f32x2){0.f, 0.f};
        acc23[j] = (f32x2){0.f, 0.f};
    }

    __syncthreads();

    // phase rows gy0..gy0+3 for this wave's b: base + j*256 + it*64 (f32x4)
    f32x4* pbase4 = reinterpret_cast<f32x4*>(
        phase + (((size_t)b * NGY + gy0) * NGX) * NK);

    const f32x2 C0 = {0.02403f, 0.02403f}, C1 = {-0.2699f, -0.2699f},
                C2 = {1.17f, 1.17f},       C3 = {-2.454f, -2.454f},
                C4 = {2.523f, 2.523f},     C5 = {-0.08003f, -0.08003f};
    const f32x2 Z2 = {0.f, 0.f}, O2 = {1.f, 1.f};

#pragma unroll
    for (int s = 0; s < 16; ++s) {
        const int j = s >> 2, it = s & 3;

        // w from LDS: lane pairs read the same 32B (2-way bcast, free)
        const f32x4 wa = lw[j * 256 + it * 64 + gxs * 2];
        const f32x4 wc = lw[j * 256 + it * 64 + gxs * 2 + 1];
        const float wf[NK] = {wa[0], wa[1], wa[2], wa[3], wc[0], wc[1], wc[2], wc[3]};

        // conv as packed pairs: xr[n] = sum_m wf[m] * y[(n-m)&7]
        f32x2 xr01 = Z2, xr23 = Z2;
#pragma unroll
        for (int m = 0; m < NK; ++m) {
            const int r = (8 - m) & 7;       // (0 - m) & 7
            const f32x2 w2  = {wf[m], wf[m]};
            const f32x2 y01 = {y[it][r],           y[it][(r + 1) & 7]};
            const f32x2 y23 = {y[it][(r + 2) & 7], y[it][(r + 3) & 7]};
            xr01 = __builtin_elementwise_fma(w2, y01, xr01);
            xr23 = __builtin_elementwise_fma(w2, y23, xr23);
        }

        // dense 1KB line-aligned burst: lane i -> byte 16*i (nontemporal)
        f32x4 q = {xr01[0], xr01[1], xr23[0], xr23[1]};
        __builtin_nontemporal_store(q, pbase4 + j * 256 + it * 64 + lane);

        // poly -> clamp -> * scale -> accumulate (packed)
        f32x2 p01 = __builtin_elementwise_fma(C0, xr01, C1);
        p01 = __builtin_elementwise_fma(p01, xr01, C2);
        p01 = __builtin_elementwise_fma(p01, xr01, C3);
        p01 = __builtin_elementwise_fma(p01, xr01, C4);
        p01 = __builtin_elementwise_fma(p01, xr01, C5);
        p01 = __builtin_elementwise_min(__builtin_elementwise_max(p01, Z2), O2);

        f32x2 p23 = __builtin_elementwise_fma(C0, xr23, C1);
        p23 = __builtin_elementwise_fma(p23, xr23, C2);
        p23 = __builtin_elementwise_fma(p23, xr23, C3);
        p23 = __builtin_elementwise_fma(p23, xr23, C4);
        p23 = __builtin_elementwise_fma(p23, xr23, C5);
        p23 = __builtin_elementwise_min(__builtin_elementwise_max(p23, Z2), O2);

        const f32x2 s01 = (it & 1) ? svo01 : sve01;
        const f32x2 s23 = (it & 1) ? svo23 : sve23;
        acc01[j] = __builtin_elementwise_fma(p01, s01, acc01[j]);
        acc23[j] = __builtin_elementwise_fma(p23, s23, acc23[j]);
    }

    // ---- tail: stage-major butterflies (16 independent shuffles per stage) ----
    float accs[4][4];
#pragma unroll
    for (int j = 0; j < 4; ++j) {
        accs[j][0] = acc01[j][0]; accs[j][1] = acc01[j][1];
        accs[j][2] = acc23[j][0]; accs[j][3] = acc23[j][1];
    }
#pragma unroll
    for (int off = 2; off < 64; off <<= 1)
#pragma unroll
        for (int j = 0; j < 4; ++j)
#pragma unroll
            for (int n = 0; n < 4; ++n)
                accs[j][n] += __shfl_xor(accs[j][n], off, 64);

#pragma unroll
    for (int j = 0; j < 4; ++j) {
        if (lane < 2) {   // lane0: k0..3, lane1: k4..7
            f32x4 v = {fmaf(2.f, accs[j][0], -128.f), fmaf(2.f, accs[j][1], -128.f),
                       fmaf(2.f, accs[j][2], -128.f), fmaf(2.f, accs[j][3], -128.f)};
            *(reinterpret_cast<f32x4*>(out + (size_t)b * 1024 + (gy0 + j) * NK) + lane) = v;
        }
    }
}

extern "C" void kernel_launch(void* const* d_in, const int* in_sizes, int n_in,
                              void* d_out, int out_size, void* d_ws, size_t ws_size,
                              hipStream_t stream) {
    const float* x     = (const float*)d_in[0];
    const float* w     = (const float*)d_in[1];
    const float* scale = (const float*)d_in[2];
    float* out = (float*)d_out;

    dim3 grid(4096);    // 128 b-groups x 32 gy-strips; 4 waves = 4 b per block
    dim3 block(256);
    hipLaunchKernelGGL(molg_pk, grid, block, 0, stream, x, w, scale, out);
}